// Round 9
// baseline (1749.176 us; speedup 1.0000x reference)
//
#include <hip/hip_runtime.h>
#include <hip/hip_fp16.h>

#define NN 100000
#define NE 1200000
#define NBUK ((NN + 127) / 128)   // 782
#define NCHUNK 128                // blocks in pass A

typedef _Float16 h8 __attribute__((ext_vector_type(8)));
typedef _Float16 h4 __attribute__((ext_vector_type(4)));
typedef float f32x4 __attribute__((ext_vector_type(4)));

// ---------------- bucketed edge sort ----------------
__global__ __launch_bounds__(1024) void k_zerob(int* bcnt) {
    int i = threadIdx.x;
    if (i <= NBUK) bcnt[i] = 0;
}

__global__ __launch_bounds__(256) void k_bhist(const int* __restrict__ col, int* __restrict__ bcnt) {
    __shared__ int lh[NBUK];
    for (int i = threadIdx.x; i < NBUK; i += 256) lh[i] = 0;
    __syncthreads();
    for (int e = blockIdx.x * 256 + threadIdx.x; e < NE; e += 256 * 256)
        atomicAdd(&lh[col[e] >> 7], 1);
    __syncthreads();
    for (int i = threadIdx.x; i < NBUK; i += 256) {
        int v = lh[i];
        if (v) atomicAdd(&bcnt[i], v);
    }
}

__global__ __launch_bounds__(1024) void k_bscan(int* __restrict__ bcnt, int* __restrict__ bcur) {
    __shared__ int s[1024];
    int tid = threadIdx.x;
    int v = (tid < NBUK) ? bcnt[tid] : 0;
    s[tid] = v;
    __syncthreads();
    #pragma unroll
    for (int d = 1; d < 1024; d <<= 1) {
        int t = (tid >= d) ? s[tid - d] : 0;
        __syncthreads();
        s[tid] += t;
        __syncthreads();
    }
    if (tid < NBUK) {
        int excl = s[tid] - v;
        bcnt[tid] = excl;
        bcur[tid] = excl;
    }
    if (tid == 0) bcnt[NBUK] = NE;
}

__global__ __launch_bounds__(256) void k_bucket(const int* __restrict__ row,
                                                const int* __restrict__ col,
                                                int* __restrict__ bcur,
                                                unsigned* __restrict__ tmp) {
    __shared__ int lh[NBUK];
    const int tid = threadIdx.x;
    const int per = (NE + NCHUNK - 1) / NCHUNK;
    const int e0 = blockIdx.x * per;
    const int e1 = (e0 + per < NE) ? (e0 + per) : NE;
    for (int i = tid; i < NBUK; i += 256) lh[i] = 0;
    __syncthreads();
    for (int e = e0 + tid; e < e1; e += 256)
        atomicAdd(&lh[col[e] >> 7], 1);
    __syncthreads();
    for (int b = tid; b < NBUK; b += 256) {
        int c = lh[b];
        if (c) lh[b] = atomicAdd(&bcur[b], c);
    }
    __syncthreads();
    for (int e = e0 + tid; e < e1; e += 256) {
        int c = col[e], r = row[e];
        int pos = atomicAdd(&lh[c >> 7], 1);
        tmp[pos] = ((unsigned)r << 7) | (unsigned)(c & 127);
    }
}

// per-bucket count -> dinv
__global__ __launch_bounds__(256) void k_cnt(const unsigned* __restrict__ tmp,
                                             const int* __restrict__ bbase,
                                             float* __restrict__ dinv) {
    __shared__ int cnt[128];
    const int b = blockIdx.x, tid = threadIdx.x;
    const int colBase = b << 7;
    const int nCols = (NN - colBase < 128) ? (NN - colBase) : 128;
    const int seg0 = bbase[b], seg1 = bbase[b + 1];
    if (tid < 128) cnt[tid] = 0;
    __syncthreads();
    for (int i = seg0 + tid; i < seg1; i += 256)
        atomicAdd(&cnt[tmp[i] & 127], 1);
    __syncthreads();
    if (tid < nCols)
        dinv[colBase + tid] = rsqrtf((float)cnt[tid] + 1.0f);
}

// ---------------- MFMA fp16 GEMM ----------------
template<int D, bool OUTH, bool BYP>
__global__ __launch_bounds__(256) void k_gemm(const float* __restrict__ X,
                                              const float* __restrict__ W,
                                              const float* __restrict__ bias,
                                              const float* __restrict__ dinv,
                                              float* __restrict__ Y,
                                              _Float16* __restrict__ Yh,
                                              const float* __restrict__ bypW,
                                              const float* __restrict__ bypb,
                                              float* __restrict__ bypOut,
                                              int n_nodes) {
    constexpr int RS = D + 8;
    constexpr int KS = D / 32;
    __shared__ _Float16 Xh[64 * RS];
    __shared__ _Float16 Wh[64 * RS];
    __shared__ float BWs[BYP ? 387 : 1];
    const int tid = threadIdx.x;
    const int n0 = blockIdx.x * 64;

    for (int i = tid; i < 64 * (D / 8); i += 256) {
        int j = i / (D / 8), d8 = (i % (D / 8)) * 8;
        const float4* wp = (const float4*)&W[j * D + d8];
        float4 w0 = wp[0], w1 = wp[1];
        h8 h = { (_Float16)w0.x, (_Float16)w0.y, (_Float16)w0.z, (_Float16)w0.w,
                 (_Float16)w1.x, (_Float16)w1.y, (_Float16)w1.z, (_Float16)w1.w };
        *(h8*)&Wh[j * RS + d8] = h;
    }
    for (int i = tid; i < 64 * (D / 8); i += 256) {
        int nl = i / (D / 8), d8 = (i % (D / 8)) * 8;
        int n = n0 + nl; if (n >= n_nodes) n = n_nodes - 1;
        const float4* xp = (const float4*)&X[(size_t)n * D + d8];
        float4 x0 = xp[0], x1 = xp[1];
        h8 h = { (_Float16)x0.x, (_Float16)x0.y, (_Float16)x0.z, (_Float16)x0.w,
                 (_Float16)x1.x, (_Float16)x1.y, (_Float16)x1.z, (_Float16)x1.w };
        *(h8*)&Xh[nl * RS + d8] = h;
    }
    if constexpr (BYP) {
        for (int idx = tid; idx < 387; idx += 256)
            BWs[idx] = (idx < 384) ? bypW[idx] : bypb[idx - 384];
    }
    __syncthreads();

    const int wid = tid >> 6, lane = tid & 63;
    const int lm = lane & 15;
    const int lq = lane >> 4;
    const int mBase = wid * 16;

    h8 bfrag[4][KS];
    #pragma unroll
    for (int t = 0; t < 4; ++t)
        #pragma unroll
        for (int s = 0; s < KS; ++s)
            bfrag[t][s] = *(const h8*)&Wh[(t * 16 + lm) * RS + s * 32 + lq * 8];

    f32x4 acc[4] = {};
    #pragma unroll
    for (int s = 0; s < KS; ++s) {
        h8 a = *(const h8*)&Xh[(mBase + lm) * RS + s * 32 + lq * 8];
        #pragma unroll
        for (int t = 0; t < 4; ++t)
            acc[t] = __builtin_amdgcn_mfma_f32_16x16x32_f16(a, bfrag[t][s], acc[t], 0, 0, 0);
    }

    float bb[4];
    if constexpr (!OUTH) {
        #pragma unroll
        for (int t = 0; t < 4; ++t) bb[t] = bias[t * 16 + lm];
    }
    const int nodeBase = n0 + mBase + lq * 4;
    #pragma unroll
    for (int r = 0; r < 4; ++r) {
        int node = nodeBase + r;
        if (node < n_nodes) {
            if constexpr (OUTH) {
                float sdv = dinv[node];
                #pragma unroll
                for (int t = 0; t < 4; ++t)
                    Yh[(size_t)node * 64 + t * 16 + lm] = (_Float16)(acc[t][r] * sdv);
            } else {
                #pragma unroll
                for (int t = 0; t < 4; ++t)
                    Y[(size_t)node * 64 + t * 16 + lm] = acc[t][r] + bb[t];
            }
        }
    }
    if constexpr (BYP) {
        if (tid < 192) {
            int nl2 = tid & 63, o = tid >> 6;
            int n = n0 + nl2;
            int nc = (n < n_nodes) ? n : (n_nodes - 1);
            const float4* xr = (const float4*)&X[(size_t)nc * D];
            float4 a4 = make_float4(0.f, 0.f, 0.f, 0.f);
            #pragma unroll 8
            for (int i = 0; i < D / 4; i++) {
                float4 v = xr[i];
                const float4 wv = *(const float4*)&BWs[o * 128 + 4 * i];
                a4.x += v.x * wv.x; a4.y += v.y * wv.y;
                a4.z += v.z * wv.z; a4.w += v.w * wv.w;
            }
            float b = BWs[384 + o] + a4.x + a4.y + a4.z + a4.w;
            if (n < n_nodes) bypOut[n * 3 + o] = b;
        }
    }
}

// ---------------- per-bucket LDS-atomic aggregation + fused epilogue ----------------
// One block per bucket (128 dest nodes). accL[c][f] (stride 68, fp32). 16 lanes/edge,
// each converts 4 fp16 feats (rotated by (c&15)*4 for bank spread) and ds-atomic-adds.
// Epilogue: 2 threads/node read the row, add self term, bn+relu(+res) or fused head.
template<bool RES, bool HEAD>
__global__ __launch_bounds__(256) void k_agg(const _Float16* __restrict__ hBh,
                                             const unsigned* __restrict__ tmp,
                                             const int* __restrict__ bbase,
                                             const float* __restrict__ dinv,
                                             const float* __restrict__ convb,
                                             const float* __restrict__ bng,
                                             const float* __restrict__ bnb,
                                             float* __restrict__ hA,
                                             const float* __restrict__ byp,
                                             const float* __restrict__ headW,
                                             const float* __restrict__ headb,
                                             float* __restrict__ out) {
    constexpr int STR = 68;              // floats; 68*4=272 B, 16B-aligned rows, bank-skewed
    __shared__ float accL[128 * STR];
    __shared__ float HWs[HEAD ? 204 : 1];
    const int tid = threadIdx.x;
    const int b = blockIdx.x;
    const int colBase = b << 7;
    const int nCols = (NN - colBase < 128) ? (NN - colBase) : 128;
    const int seg0 = bbase[b], seg1 = bbase[b + 1];

    for (int i = tid; i < 128 * STR / 4; i += 256)
        ((f32x4*)accL)[i] = (f32x4){0.f, 0.f, 0.f, 0.f};
    if constexpr (HEAD) {
        for (int i = tid; i < 204; i += 256)
            HWs[i] = (i < 201) ? headW[i] : headb[i - 201];
    }
    __syncthreads();

    const int el = tid >> 4, li = tid & 15;
    for (int i = seg0 + el; i < seg1; i += 16) {
        unsigned v = tmp[i];
        int c = v & 127u;
        int r = (int)(v >> 7);
        int f = ((li << 2) + ((c & 15) << 2)) & 63;     // rotated 4-feat slot
        h4 raw = *(const h4*)(hBh + ((size_t)r << 6) + f);
        float* dst = &accL[c * STR + f];
        atomicAdd(dst + 0, (float)raw[0]);
        atomicAdd(dst + 1, (float)raw[1]);
        atomicAdd(dst + 2, (float)raw[2]);
        atomicAdd(dst + 3, (float)raw[3]);
    }
    __syncthreads();

    const int col = tid >> 1, f0 = (tid & 1) * 32;
    if (col < nCols) {
        const int n = colBase + col;
        const float dv = dinv[n];
        const float bnscale = rsqrtf(1.0f + 1e-5f);
        float v[32];
        #pragma unroll
        for (int q = 0; q < 4; ++q) {
            h8 s = *(const h8*)(hBh + ((size_t)n << 6) + f0 + q * 8);
            float4 a0 = *(const float4*)&accL[col * STR + f0 + q * 8];
            float4 a1 = *(const float4*)&accL[col * STR + f0 + q * 8 + 4];
            float a[8] = { a0.x, a0.y, a0.z, a0.w, a1.x, a1.y, a1.z, a1.w };
            #pragma unroll
            for (int j = 0; j < 8; ++j) {
                int fj = f0 + q * 8 + j;
                float t = (a[j] + (float)s[j]) * dv + convb[fj];
                v[q * 8 + j] = fmaxf(t * (bng[fj] * bnscale) + bnb[fj], 0.0f);
            }
        }
        if constexpr (!HEAD) {
            size_t o = ((size_t)n << 6) + f0;
            #pragma unroll
            for (int q = 0; q < 8; ++q) {
                float4 w4 = make_float4(v[q * 4], v[q * 4 + 1], v[q * 4 + 2], v[q * 4 + 3]);
                if constexpr (RES) {
                    float4 old = *(const float4*)&hA[o + q * 4];
                    w4.x += old.x; w4.y += old.y; w4.z += old.z; w4.w += old.w;
                }
                *(float4*)&hA[o + q * 4] = w4;
            }
        } else {
            float p[3];
            #pragma unroll
            for (int o = 0; o < 3; ++o) {
                float t = 0.f;
                #pragma unroll
                for (int j = 0; j < 32; ++j) t += v[j] * HWs[o * 67 + f0 + j];
                p[o] = t;
            }
            #pragma unroll
            for (int o = 0; o < 3; ++o) p[o] += __shfl_xor(p[o], 1, 64);
            float b0 = byp[n * 3], b1 = byp[n * 3 + 1], b2 = byp[n * 3 + 2];
            #pragma unroll
            for (int o = 0; o < 3; ++o)
                p[o] += b0 * HWs[o * 67 + 64] + b1 * HWs[o * 67 + 65] + b2 * HWs[o * 67 + 66]
                      + HWs[201 + o];
            if ((tid & 1) == 0) {
                float kappa = fminf(fmaxf(p[0] * 5.0f + 2.5f, 0.2f), 10.0f);
                float tau   = fminf(fmaxf(p[2] + 0.5f, 0.05f), 2.0f);
                out[(size_t)n * 3]     = kappa;
                out[(size_t)n * 3 + 1] = p[1];
                out[(size_t)n * 3 + 2] = tau;
            }
        }
    }
}

extern "C" void kernel_launch(void* const* d_in, const int* in_sizes, int n_in,
                              void* d_out, int out_size, void* d_ws, size_t ws_size,
                              hipStream_t stream) {
    const float* x     = (const float*)d_in[0];
    const int*   ei    = (const int*)d_in[1];
    const int*   row   = ei;
    const int*   col   = ei + NE;
    const float* projW = (const float*)d_in[2];
    const float* projb = (const float*)d_in[3];
    const float* convW[3] = { (const float*)d_in[4], (const float*)d_in[8],  (const float*)d_in[12] };
    const float* convb[3] = { (const float*)d_in[5], (const float*)d_in[9],  (const float*)d_in[13] };
    const float* bng[3]   = { (const float*)d_in[6], (const float*)d_in[10], (const float*)d_in[14] };
    const float* bnb[3]   = { (const float*)d_in[7], (const float*)d_in[11], (const float*)d_in[15] };
    const float* bypW  = (const float*)d_in[16];
    const float* bypb  = (const float*)d_in[17];
    const float* headW = (const float*)d_in[18];
    const float* headb = (const float*)d_in[19];
    float* out = (float*)d_out;

    float*    ws   = (float*)d_ws;
    float*    dinv = ws;                                  // 102400 floats
    float*    hA   = ws + 102400;                         // NN*64 fp32
    _Float16* hBh  = (_Float16*)(hA + (size_t)NN * 64);   // NN*64 fp16
    float*    byp  = (float*)(hBh + (size_t)NN * 64);     // NN*3 (+pad)
    unsigned* tmp  = (unsigned*)(byp + 300032);           // NE (persistent — no aliasing)
    int*      bcnt = (int*)(tmp + NE);                    // NBUK+1 (pad 784)
    int*      bcur = bcnt + 784;                          // NBUK

    // bucket-sorted edge list + dinv
    k_zerob<<<1, 1024, 0, stream>>>(bcnt);
    k_bhist<<<256, 256, 0, stream>>>(col, bcnt);
    k_bscan<<<1, 1024, 0, stream>>>(bcnt, bcur);
    k_bucket<<<NCHUNK, 256, 0, stream>>>(row, col, bcur, tmp);
    k_cnt<<<NBUK, 256, 0, stream>>>(tmp, bcnt, dinv);

    // proj: hA = x @ projW.T + projb  (fp32 out) + byp = x @ bypW.T + bypb
    k_gemm<128, false, true><<<(NN + 63) / 64, 256, 0, stream>>>(
        x, projW, projb, nullptr, hA, nullptr, bypW, bypb, byp, NN);

    for (int l = 0; l < 3; l++) {
        // hBh = (hA @ convW.T) * dinv   (fp16 out, bias deferred)
        k_gemm<64, true, false><<<(NN + 63) / 64, 256, 0, stream>>>(
            hA, convW[l], nullptr, dinv, nullptr, hBh, nullptr, nullptr, nullptr, NN);
        if (l < 2)
            k_agg<true, false><<<NBUK, 256, 0, stream>>>(
                hBh, tmp, bcnt, dinv, convb[l], bng[l], bnb[l], hA,
                nullptr, nullptr, nullptr, nullptr);
        else
            k_agg<false, true><<<NBUK, 256, 0, stream>>>(
                hBh, tmp, bcnt, dinv, convb[l], bng[l], bnb[l], nullptr,
                byp, headW, headb, out);
    }
}

// Round 10
// 368.048 us; speedup vs baseline: 4.7526x; 4.7526x over previous
//
#include <hip/hip_runtime.h>
#include <hip/hip_fp16.h>

#define NN 100000
#define NE 1200000
#define NBUK ((NN + 127) / 128)   // 782
#define NCHUNK 128                // blocks in pass A

typedef _Float16 h8 __attribute__((ext_vector_type(8)));
typedef float f32x4 __attribute__((ext_vector_type(4)));

// ---------------- bucketed CSR build ----------------
__global__ __launch_bounds__(1024) void k_zerob(int* bcnt) {
    int i = threadIdx.x;
    if (i <= NBUK) bcnt[i] = 0;
}

__global__ __launch_bounds__(256) void k_bhist(const int* __restrict__ col, int* __restrict__ bcnt) {
    __shared__ int lh[NBUK];
    for (int i = threadIdx.x; i < NBUK; i += 256) lh[i] = 0;
    __syncthreads();
    for (int e = blockIdx.x * 256 + threadIdx.x; e < NE; e += 256 * 256)
        atomicAdd(&lh[col[e] >> 7], 1);
    __syncthreads();
    for (int i = threadIdx.x; i < NBUK; i += 256) {
        int v = lh[i];
        if (v) atomicAdd(&bcnt[i], v);
    }
}

__global__ __launch_bounds__(1024) void k_bscan(int* __restrict__ bcnt, int* __restrict__ bcur) {
    __shared__ int s[1024];
    int tid = threadIdx.x;
    int v = (tid < NBUK) ? bcnt[tid] : 0;
    s[tid] = v;
    __syncthreads();
    #pragma unroll
    for (int d = 1; d < 1024; d <<= 1) {
        int t = (tid >= d) ? s[tid - d] : 0;
        __syncthreads();
        s[tid] += t;
        __syncthreads();
    }
    if (tid < NBUK) {
        int excl = s[tid] - v;
        bcnt[tid] = excl;
        bcur[tid] = excl;
    }
    if (tid == 0) bcnt[NBUK] = NE;
}

__global__ __launch_bounds__(256) void k_bucket(const int* __restrict__ row,
                                                const int* __restrict__ col,
                                                int* __restrict__ bcur,
                                                unsigned* __restrict__ tmp) {
    __shared__ int lh[NBUK];
    const int tid = threadIdx.x;
    const int per = (NE + NCHUNK - 1) / NCHUNK;
    const int e0 = blockIdx.x * per;
    const int e1 = (e0 + per < NE) ? (e0 + per) : NE;
    for (int i = tid; i < NBUK; i += 256) lh[i] = 0;
    __syncthreads();
    for (int e = e0 + tid; e < e1; e += 256)
        atomicAdd(&lh[col[e] >> 7], 1);
    __syncthreads();
    for (int b = tid; b < NBUK; b += 256) {
        int c = lh[b];
        if (c) lh[b] = atomicAdd(&bcur[b], c);
    }
    __syncthreads();
    for (int e = e0 + tid; e < e1; e += 256) {
        int c = col[e], r = row[e];
        int pos = atomicAdd(&lh[c >> 7], 1);
        tmp[pos] = ((unsigned)r << 7) | (unsigned)(c & 127);
    }
}

__global__ __launch_bounds__(256) void k_build(const unsigned* __restrict__ tmp,
                                               const int* __restrict__ bbase,
                                               int* __restrict__ off,
                                               float* __restrict__ dinv,
                                               int* __restrict__ csr_row) {
    __shared__ int cnt[128], s[128], cur[128];
    const int b = blockIdx.x, tid = threadIdx.x;
    const int colBase = b << 7;
    const int nCols = (NN - colBase < 128) ? (NN - colBase) : 128;
    const int seg0 = bbase[b], seg1 = bbase[b + 1];
    if (tid < 128) cnt[tid] = 0;
    __syncthreads();
    for (int i = seg0 + tid; i < seg1; i += 256)
        atomicAdd(&cnt[tmp[i] & 127], 1);
    __syncthreads();
    if (tid < 128) s[tid] = cnt[tid];
    __syncthreads();
    #pragma unroll
    for (int d = 1; d < 128; d <<= 1) {
        int t = (tid < 128 && tid >= d) ? s[tid - d] : 0;
        __syncthreads();
        if (tid < 128) s[tid] += t;
        __syncthreads();
    }
    if (tid < nCols) {
        int exc = seg0 + s[tid] - cnt[tid];
        off[colBase + tid] = exc;
        cur[tid] = exc;
        dinv[colBase + tid] = rsqrtf((float)cnt[tid] + 1.0f);
    }
    if (b == 0 && tid == 0) off[NN] = NE;
    __syncthreads();
    for (int i = seg0 + tid; i < seg1; i += 256) {
        unsigned v = tmp[i];
        int pos = atomicAdd(&cur[v & 127u], 1);
        csr_row[pos] = (int)(v >> 7);
    }
}

// ---------------- MFMA fp16 GEMM ----------------
template<int D, bool OUTH, bool BYP>
__global__ __launch_bounds__(256) void k_gemm(const float* __restrict__ X,
                                              const float* __restrict__ W,
                                              const float* __restrict__ bias,
                                              const float* __restrict__ dinv,
                                              float* __restrict__ Y,
                                              _Float16* __restrict__ Yh,
                                              const float* __restrict__ bypW,
                                              const float* __restrict__ bypb,
                                              float* __restrict__ bypOut,
                                              int n_nodes) {
    constexpr int RS = D + 8;
    constexpr int KS = D / 32;
    __shared__ _Float16 Xh[64 * RS];
    __shared__ _Float16 Wh[64 * RS];
    __shared__ float BWs[BYP ? 387 : 1];
    const int tid = threadIdx.x;
    const int n0 = blockIdx.x * 64;

    for (int i = tid; i < 64 * (D / 8); i += 256) {
        int j = i / (D / 8), d8 = (i % (D / 8)) * 8;
        const float4* wp = (const float4*)&W[j * D + d8];
        float4 w0 = wp[0], w1 = wp[1];
        h8 h = { (_Float16)w0.x, (_Float16)w0.y, (_Float16)w0.z, (_Float16)w0.w,
                 (_Float16)w1.x, (_Float16)w1.y, (_Float16)w1.z, (_Float16)w1.w };
        *(h8*)&Wh[j * RS + d8] = h;
    }
    for (int i = tid; i < 64 * (D / 8); i += 256) {
        int nl = i / (D / 8), d8 = (i % (D / 8)) * 8;
        int n = n0 + nl; if (n >= n_nodes) n = n_nodes - 1;
        const float4* xp = (const float4*)&X[(size_t)n * D + d8];
        float4 x0 = xp[0], x1 = xp[1];
        h8 h = { (_Float16)x0.x, (_Float16)x0.y, (_Float16)x0.z, (_Float16)x0.w,
                 (_Float16)x1.x, (_Float16)x1.y, (_Float16)x1.z, (_Float16)x1.w };
        *(h8*)&Xh[nl * RS + d8] = h;
    }
    if constexpr (BYP) {
        for (int idx = tid; idx < 387; idx += 256)
            BWs[idx] = (idx < 384) ? bypW[idx] : bypb[idx - 384];
    }
    __syncthreads();

    const int wid = tid >> 6, lane = tid & 63;
    const int lm = lane & 15;
    const int lq = lane >> 4;
    const int mBase = wid * 16;

    h8 bfrag[4][KS];
    #pragma unroll
    for (int t = 0; t < 4; ++t)
        #pragma unroll
        for (int s = 0; s < KS; ++s)
            bfrag[t][s] = *(const h8*)&Wh[(t * 16 + lm) * RS + s * 32 + lq * 8];

    f32x4 acc[4] = {};
    #pragma unroll
    for (int s = 0; s < KS; ++s) {
        h8 a = *(const h8*)&Xh[(mBase + lm) * RS + s * 32 + lq * 8];
        #pragma unroll
        for (int t = 0; t < 4; ++t)
            acc[t] = __builtin_amdgcn_mfma_f32_16x16x32_f16(a, bfrag[t][s], acc[t], 0, 0, 0);
    }

    float bb[4];
    if constexpr (!OUTH) {
        #pragma unroll
        for (int t = 0; t < 4; ++t) bb[t] = bias[t * 16 + lm];
    }
    const int nodeBase = n0 + mBase + lq * 4;
    #pragma unroll
    for (int r = 0; r < 4; ++r) {
        int node = nodeBase + r;
        if (node < n_nodes) {
            if constexpr (OUTH) {
                float sdv = dinv[node];
                #pragma unroll
                for (int t = 0; t < 4; ++t)
                    Yh[(size_t)node * 64 + t * 16 + lm] = (_Float16)(acc[t][r] * sdv);
            } else {
                #pragma unroll
                for (int t = 0; t < 4; ++t)
                    Y[(size_t)node * 64 + t * 16 + lm] = acc[t][r] + bb[t];
            }
        }
    }
    if constexpr (BYP) {
        if (tid < 192) {
            int nl2 = tid & 63, o = tid >> 6;
            int n = n0 + nl2;
            int nc = (n < n_nodes) ? n : (n_nodes - 1);
            const float4* xr = (const float4*)&X[(size_t)nc * D];
            float4 a4 = make_float4(0.f, 0.f, 0.f, 0.f);
            #pragma unroll 8
            for (int i = 0; i < D / 4; i++) {
                float4 v = xr[i];
                const float4 wv = *(const float4*)&BWs[o * 128 + 4 * i];
                a4.x += v.x * wv.x; a4.y += v.y * wv.y;
                a4.z += v.z * wv.z; a4.w += v.w * wv.w;
            }
            float b = BWs[384 + o] + a4.x + a4.y + a4.z + a4.w;
            if (n < n_nodes) bypOut[n * 3 + o] = b;
        }
    }
}

// ---------------- fused pull-aggregation (packed fp16, 16 edges/iter, 2 loads in flight) ----------------
template<bool RES, bool HEAD>
__global__ __launch_bounds__(256) void k_gather(const _Float16* __restrict__ hBh,
                                                const float* __restrict__ dinv,
                                                const int* __restrict__ off,
                                                const int* __restrict__ csr_row,
                                                const float* __restrict__ convb,
                                                const float* __restrict__ bng,
                                                const float* __restrict__ bnb,
                                                float* __restrict__ hA,
                                                const float* __restrict__ byp,
                                                const float* __restrict__ headW,
                                                const float* __restrict__ headb,
                                                float* __restrict__ out) {
    __shared__ float HWs[HEAD ? 204 : 1];
    const int tid = threadIdx.x;
    if constexpr (HEAD) {
        for (int i = tid; i < 204; i += 256)
            HWs[i] = (i < 201) ? headW[i] : headb[i - 201];
        __syncthreads();
    }
    const int n = blockIdx.x * 4 + (tid >> 6);   // grid = NN/4 exactly
    const int lane = tid & 63;
    const int g = lane >> 3, s = lane & 7;
    const int f0 = s * 8;

    const int e0 = off[n], eEnd = off[n + 1];
    h8 acch = (h8)(_Float16)0;
    // 16 edges per iteration: lane-group g handles base+g and base+g+8 (2 loads in flight)
    for (int base = e0; base < eEnd; base += 16) {
        int i0 = base + g, i1 = base + g + 8;
        bool v0 = i0 < eEnd, v1 = i1 < eEnd;
        int r0 = csr_row[v0 ? i0 : e0];
        int r1 = csr_row[v1 ? i1 : e0];
        h8 raw0 = *(const h8*)(hBh + ((size_t)r0 << 6) + f0);
        h8 raw1 = *(const h8*)(hBh + ((size_t)r1 << 6) + f0);
        _Float16 w0 = v0 ? (_Float16)1.0f : (_Float16)0.0f;
        _Float16 w1 = v1 ? (_Float16)1.0f : (_Float16)0.0f;
        h8 wv0 = { w0, w0, w0, w0, w0, w0, w0, w0 };
        h8 wv1 = { w1, w1, w1, w1, w1, w1, w1, w1 };
        acch = raw0 * wv0 + acch;
        acch = raw1 * wv1 + acch;
    }
    // butterfly over edge-groups: packed adds, 4 int shuffles per level
    #pragma unroll
    for (int m = 8; m < 64; m <<= 1) {
        int4 ai = *(int4*)&acch;
        int4 bi;
        bi.x = __shfl_xor(ai.x, m, 64);
        bi.y = __shfl_xor(ai.y, m, 64);
        bi.z = __shfl_xor(ai.z, m, 64);
        bi.w = __shfl_xor(ai.w, m, 64);
        acch = acch + *(h8*)&bi;
    }
    // self-loop term
    acch = acch + *(const h8*)(hBh + ((size_t)n << 6) + f0);

    float acc[8];
    #pragma unroll
    for (int j = 0; j < 8; ++j) acc[j] = (float)acch[j];

    const float dv = dinv[n];
    const float bnscale = rsqrtf(1.0f + 1e-5f);
    float v[8];
    #pragma unroll
    for (int j = 0; j < 8; ++j) {
        float sc = bng[f0 + j] * bnscale;
        v[j] = fmaxf((acc[j] * dv + convb[f0 + j]) * sc + bnb[f0 + j], 0.0f);
    }
    if constexpr (!HEAD) {
        if (g == 0) {
            size_t o = ((size_t)n << 6) + f0;
            if constexpr (RES) {
                #pragma unroll
                for (int j = 0; j < 8; ++j) v[j] += hA[o + j];
            }
            *(float4*)&hA[o]     = make_float4(v[0], v[1], v[2], v[3]);
            *(float4*)&hA[o + 4] = make_float4(v[4], v[5], v[6], v[7]);
        }
    } else {
        float p[3];
        #pragma unroll
        for (int o = 0; o < 3; ++o) {
            float t = 0.f;
            #pragma unroll
            for (int j = 0; j < 8; ++j) t += v[j] * HWs[o * 67 + f0 + j];
            p[o] = t;
        }
        #pragma unroll
        for (int m = 1; m < 8; m <<= 1) {
            #pragma unroll
            for (int o = 0; o < 3; ++o) p[o] += __shfl_xor(p[o], m, 64);
        }
        float b0 = byp[n * 3], b1 = byp[n * 3 + 1], b2 = byp[n * 3 + 2];
        #pragma unroll
        for (int o = 0; o < 3; ++o)
            p[o] += b0 * HWs[o * 67 + 64] + b1 * HWs[o * 67 + 65] + b2 * HWs[o * 67 + 66]
                  + HWs[201 + o];
        if (lane == 0) {
            float kappa = fminf(fmaxf(p[0] * 5.0f + 2.5f, 0.2f), 10.0f);
            float tau   = fminf(fmaxf(p[2] + 0.5f, 0.05f), 2.0f);
            out[(size_t)n * 3]     = kappa;
            out[(size_t)n * 3 + 1] = p[1];
            out[(size_t)n * 3 + 2] = tau;
        }
    }
}

extern "C" void kernel_launch(void* const* d_in, const int* in_sizes, int n_in,
                              void* d_out, int out_size, void* d_ws, size_t ws_size,
                              hipStream_t stream) {
    const float* x     = (const float*)d_in[0];
    const int*   ei    = (const int*)d_in[1];
    const int*   row   = ei;
    const int*   col   = ei + NE;
    const float* projW = (const float*)d_in[2];
    const float* projb = (const float*)d_in[3];
    const float* convW[3] = { (const float*)d_in[4], (const float*)d_in[8],  (const float*)d_in[12] };
    const float* convb[3] = { (const float*)d_in[5], (const float*)d_in[9],  (const float*)d_in[13] };
    const float* bng[3]   = { (const float*)d_in[6], (const float*)d_in[10], (const float*)d_in[14] };
    const float* bnb[3]   = { (const float*)d_in[7], (const float*)d_in[11], (const float*)d_in[15] };
    const float* bypW  = (const float*)d_in[16];
    const float* bypb  = (const float*)d_in[17];
    const float* headW = (const float*)d_in[18];
    const float* headb = (const float*)d_in[19];
    float* out = (float*)d_out;

    float*    ws   = (float*)d_ws;
    float*    dinv = ws;                                  // 102400 floats
    float*    hA   = ws + 102400;                         // NN*64 fp32
    _Float16* hBh  = (_Float16*)(hA + (size_t)NN * 64);   // NN*64 fp16
    float*    byp  = (float*)(hBh + (size_t)NN * 64);     // NN*3 (+pad)
    int*      off     = (int*)(byp + 300032);             // NN+1 (pad 100096)
    int*      csr_row = off + 100096;                     // NE
    int*      bcnt    = csr_row + NE;                     // NBUK+1 (pad 784)
    int*      bcur    = bcnt + 784;                       // NBUK
    unsigned* tmp     = (unsigned*)hA;                    // aliases hA (consumed before proj)

    // bucketed CSR build (+dinv +off)
    k_zerob<<<1, 1024, 0, stream>>>(bcnt);
    k_bhist<<<256, 256, 0, stream>>>(col, bcnt);
    k_bscan<<<1, 1024, 0, stream>>>(bcnt, bcur);
    k_bucket<<<NCHUNK, 256, 0, stream>>>(row, col, bcur, tmp);
    k_build<<<NBUK, 256, 0, stream>>>(tmp, bcnt, off, dinv, csr_row);

    // proj: hA = x @ projW.T + projb  (fp32 out) + byp = x @ bypW.T + bypb
    k_gemm<128, false, true><<<(NN + 63) / 64, 256, 0, stream>>>(
        x, projW, projb, nullptr, hA, nullptr, bypW, bypb, byp, NN);

    for (int l = 0; l < 3; l++) {
        // hBh = (hA @ convW.T) * dinv   (fp16 out, bias deferred)
        k_gemm<64, true, false><<<(NN + 63) / 64, 256, 0, stream>>>(
            hA, convW[l], nullptr, dinv, nullptr, hBh, nullptr, nullptr, nullptr, NN);
        if (l < 2)
            k_gather<true, false><<<NN / 4, 256, 0, stream>>>(
                hBh, dinv, off, csr_row, convb[l], bng[l], bnb[l], hA,
                nullptr, nullptr, nullptr, nullptr);
        else
            k_gather<false, true><<<NN / 4, 256, 0, stream>>>(
                hBh, dinv, off, csr_row, convb[l], bng[l], bnb[l], nullptr,
                byp, headW, headb, out);
    }
}

// Round 11
// 314.987 us; speedup vs baseline: 5.5532x; 1.1685x over previous
//
#include <hip/hip_runtime.h>
#include <hip/hip_fp16.h>

#define NN 100000
#define NE 1200000
#define NBUK ((NN + 127) / 128)   // 782
#define NCHUNK 128                // blocks in pass A

typedef _Float16 h8 __attribute__((ext_vector_type(8)));
typedef float f32x4 __attribute__((ext_vector_type(4)));

// ---------------- bucketed CSR build ----------------
__global__ __launch_bounds__(1024) void k_zerob(int* bcnt) {
    int i = threadIdx.x;
    if (i <= NBUK) bcnt[i] = 0;
}

__global__ __launch_bounds__(256) void k_bhist(const int* __restrict__ col, int* __restrict__ bcnt) {
    __shared__ int lh[NBUK];
    for (int i = threadIdx.x; i < NBUK; i += 256) lh[i] = 0;
    __syncthreads();
    for (int e = blockIdx.x * 256 + threadIdx.x; e < NE; e += 256 * 256)
        atomicAdd(&lh[col[e] >> 7], 1);
    __syncthreads();
    for (int i = threadIdx.x; i < NBUK; i += 256) {
        int v = lh[i];
        if (v) atomicAdd(&bcnt[i], v);
    }
}

__global__ __launch_bounds__(1024) void k_bscan(int* __restrict__ bcnt, int* __restrict__ bcur) {
    __shared__ int s[1024];
    int tid = threadIdx.x;
    int v = (tid < NBUK) ? bcnt[tid] : 0;
    s[tid] = v;
    __syncthreads();
    #pragma unroll
    for (int d = 1; d < 1024; d <<= 1) {
        int t = (tid >= d) ? s[tid - d] : 0;
        __syncthreads();
        s[tid] += t;
        __syncthreads();
    }
    if (tid < NBUK) {
        int excl = s[tid] - v;
        bcnt[tid] = excl;
        bcur[tid] = excl;
    }
    if (tid == 0) bcnt[NBUK] = NE;
}

__global__ __launch_bounds__(256) void k_bucket(const int* __restrict__ row,
                                                const int* __restrict__ col,
                                                int* __restrict__ bcur,
                                                unsigned* __restrict__ tmp) {
    __shared__ int lh[NBUK];
    const int tid = threadIdx.x;
    const int per = (NE + NCHUNK - 1) / NCHUNK;
    const int e0 = blockIdx.x * per;
    const int e1 = (e0 + per < NE) ? (e0 + per) : NE;
    for (int i = tid; i < NBUK; i += 256) lh[i] = 0;
    __syncthreads();
    for (int e = e0 + tid; e < e1; e += 256)
        atomicAdd(&lh[col[e] >> 7], 1);
    __syncthreads();
    for (int b = tid; b < NBUK; b += 256) {
        int c = lh[b];
        if (c) lh[b] = atomicAdd(&bcur[b], c);
    }
    __syncthreads();
    for (int e = e0 + tid; e < e1; e += 256) {
        int c = col[e], r = row[e];
        int pos = atomicAdd(&lh[c >> 7], 1);
        tmp[pos] = ((unsigned)r << 7) | (unsigned)(c & 127);
    }
}

__global__ __launch_bounds__(256) void k_build(const unsigned* __restrict__ tmp,
                                               const int* __restrict__ bbase,
                                               int* __restrict__ off,
                                               float* __restrict__ dinv,
                                               int* __restrict__ csr_row) {
    __shared__ int cnt[128], s[128], cur[128];
    const int b = blockIdx.x, tid = threadIdx.x;
    const int colBase = b << 7;
    const int nCols = (NN - colBase < 128) ? (NN - colBase) : 128;
    const int seg0 = bbase[b], seg1 = bbase[b + 1];
    if (tid < 128) cnt[tid] = 0;
    __syncthreads();
    for (int i = seg0 + tid; i < seg1; i += 256)
        atomicAdd(&cnt[tmp[i] & 127], 1);
    __syncthreads();
    if (tid < 128) s[tid] = cnt[tid];
    __syncthreads();
    #pragma unroll
    for (int d = 1; d < 128; d <<= 1) {
        int t = (tid < 128 && tid >= d) ? s[tid - d] : 0;
        __syncthreads();
        if (tid < 128) s[tid] += t;
        __syncthreads();
    }
    if (tid < nCols) {
        int exc = seg0 + s[tid] - cnt[tid];
        off[colBase + tid] = exc;
        cur[tid] = exc;
        dinv[colBase + tid] = rsqrtf((float)cnt[tid] + 1.0f);
    }
    if (b == 0 && tid == 0) off[NN] = NE;
    __syncthreads();
    for (int i = seg0 + tid; i < seg1; i += 256) {
        unsigned v = tmp[i];
        int pos = atomicAdd(&cur[v & 127u], 1);
        csr_row[pos] = (int)(v >> 7);
    }
}

// ---------------- MFMA fp16 GEMM ----------------
template<int D, bool OUTH, bool BYP>
__global__ __launch_bounds__(256) void k_gemm(const float* __restrict__ X,
                                              const float* __restrict__ W,
                                              const float* __restrict__ bias,
                                              const float* __restrict__ dinv,
                                              float* __restrict__ Y,
                                              _Float16* __restrict__ Yh,
                                              const float* __restrict__ bypW,
                                              const float* __restrict__ bypb,
                                              float* __restrict__ bypOut,
                                              int n_nodes) {
    constexpr int RS = D + 8;
    constexpr int KS = D / 32;
    __shared__ _Float16 Xh[64 * RS];
    __shared__ _Float16 Wh[64 * RS];
    __shared__ float BWs[BYP ? 387 : 1];
    const int tid = threadIdx.x;
    const int n0 = blockIdx.x * 64;

    for (int i = tid; i < 64 * (D / 8); i += 256) {
        int j = i / (D / 8), d8 = (i % (D / 8)) * 8;
        const float4* wp = (const float4*)&W[j * D + d8];
        float4 w0 = wp[0], w1 = wp[1];
        h8 h = { (_Float16)w0.x, (_Float16)w0.y, (_Float16)w0.z, (_Float16)w0.w,
                 (_Float16)w1.x, (_Float16)w1.y, (_Float16)w1.z, (_Float16)w1.w };
        *(h8*)&Wh[j * RS + d8] = h;
    }
    for (int i = tid; i < 64 * (D / 8); i += 256) {
        int nl = i / (D / 8), d8 = (i % (D / 8)) * 8;
        int n = n0 + nl; if (n >= n_nodes) n = n_nodes - 1;
        const float4* xp = (const float4*)&X[(size_t)n * D + d8];
        float4 x0 = xp[0], x1 = xp[1];
        h8 h = { (_Float16)x0.x, (_Float16)x0.y, (_Float16)x0.z, (_Float16)x0.w,
                 (_Float16)x1.x, (_Float16)x1.y, (_Float16)x1.z, (_Float16)x1.w };
        *(h8*)&Xh[nl * RS + d8] = h;
    }
    if constexpr (BYP) {
        for (int idx = tid; idx < 387; idx += 256)
            BWs[idx] = (idx < 384) ? bypW[idx] : bypb[idx - 384];
    }
    __syncthreads();

    const int wid = tid >> 6, lane = tid & 63;
    const int lm = lane & 15;
    const int lq = lane >> 4;
    const int mBase = wid * 16;

    h8 bfrag[4][KS];
    #pragma unroll
    for (int t = 0; t < 4; ++t)
        #pragma unroll
        for (int s = 0; s < KS; ++s)
            bfrag[t][s] = *(const h8*)&Wh[(t * 16 + lm) * RS + s * 32 + lq * 8];

    f32x4 acc[4] = {};
    #pragma unroll
    for (int s = 0; s < KS; ++s) {
        h8 a = *(const h8*)&Xh[(mBase + lm) * RS + s * 32 + lq * 8];
        #pragma unroll
        for (int t = 0; t < 4; ++t)
            acc[t] = __builtin_amdgcn_mfma_f32_16x16x32_f16(a, bfrag[t][s], acc[t], 0, 0, 0);
    }

    float bb[4];
    if constexpr (!OUTH) {
        #pragma unroll
        for (int t = 0; t < 4; ++t) bb[t] = bias[t * 16 + lm];
    }
    const int nodeBase = n0 + mBase + lq * 4;
    #pragma unroll
    for (int r = 0; r < 4; ++r) {
        int node = nodeBase + r;
        if (node < n_nodes) {
            if constexpr (OUTH) {
                float sdv = dinv[node];
                #pragma unroll
                for (int t = 0; t < 4; ++t)
                    Yh[(size_t)node * 64 + t * 16 + lm] = (_Float16)(acc[t][r] * sdv);
            } else {
                #pragma unroll
                for (int t = 0; t < 4; ++t)
                    Y[(size_t)node * 64 + t * 16 + lm] = acc[t][r] + bb[t];
            }
        }
    }
    if constexpr (BYP) {
        if (tid < 192) {
            int nl2 = tid & 63, o = tid >> 6;
            int n = n0 + nl2;
            int nc = (n < n_nodes) ? n : (n_nodes - 1);
            const float4* xr = (const float4*)&X[(size_t)nc * D];
            float4 a4 = make_float4(0.f, 0.f, 0.f, 0.f);
            #pragma unroll 8
            for (int i = 0; i < D / 4; i++) {
                float4 v = xr[i];
                const float4 wv = *(const float4*)&BWs[o * 128 + 4 * i];
                a4.x += v.x * wv.x; a4.y += v.y * wv.y;
                a4.z += v.z * wv.z; a4.w += v.w * wv.w;
            }
            float b = BWs[384 + o] + a4.x + a4.y + a4.z + a4.w;
            if (n < n_nodes) bypOut[n * 3 + o] = b;
        }
    }
}

// ---------------- pull-aggregation: 8 nodes/wave, 8 lanes/node (no butterfly) ----------------
// lane = (nodeInWave = lane>>3, oct = lane&7). Each lane owns 8 features of one node.
// All 8 lanes of a node read the same csr_row[e] (broadcast) and one h8 row-slice.
template<bool RES, bool HEAD>
__global__ __launch_bounds__(256) void k_gather(const _Float16* __restrict__ hBh,
                                                const float* __restrict__ dinv,
                                                const int* __restrict__ off,
                                                const int* __restrict__ csr_row,
                                                const float* __restrict__ convb,
                                                const float* __restrict__ bng,
                                                const float* __restrict__ bnb,
                                                float* __restrict__ hA,
                                                const float* __restrict__ byp,
                                                const float* __restrict__ headW,
                                                const float* __restrict__ headb,
                                                float* __restrict__ out) {
    __shared__ float HWs[HEAD ? 204 : 1];
    const int tid = threadIdx.x;
    if constexpr (HEAD) {
        for (int i = tid; i < 204; i += 256)
            HWs[i] = (i < 201) ? headW[i] : headb[i - 201];
        __syncthreads();
    }
    const int wid = tid >> 6, lane = tid & 63;
    const int n = blockIdx.x * 32 + wid * 8 + (lane >> 3);   // grid = NN/32 exactly
    const int oct = lane & 7;
    const int f0 = oct * 8;

    const int e0 = off[n], eEnd = off[n + 1];
    const int deg = eEnd - e0;
    // wave-uniform max degree over the 8 node-groups (3 shuffles)
    int m = deg;
    #pragma unroll
    for (int mask = 8; mask < 64; mask <<= 1) {
        int o = __shfl_xor(m, mask, 64);
        m = (o > m) ? o : m;
    }

    h8 acch = *(const h8*)(hBh + ((size_t)n << 6) + f0);   // self-loop term
    const h8 zero = (h8)(_Float16)0;
    for (int it = 0; it < m; it += 2) {
        bool v0 = it < deg, v1 = it + 1 < deg;
        int i0 = e0 + it, i1 = i0 + 1;
        int r0 = csr_row[v0 ? i0 : 0];
        int r1 = csr_row[v1 ? i1 : 0];
        h8 raw0 = *(const h8*)(hBh + ((size_t)r0 << 6) + f0);
        h8 raw1 = *(const h8*)(hBh + ((size_t)r1 << 6) + f0);
        acch = acch + (v0 ? raw0 : zero);
        acch = acch + (v1 ? raw1 : zero);
    }

    const float dv = dinv[n];
    const float bnscale = rsqrtf(1.0f + 1e-5f);
    const float4 cb0 = *(const float4*)&convb[f0], cb1 = *(const float4*)&convb[f0 + 4];
    const float4 g0  = *(const float4*)&bng[f0],  g1  = *(const float4*)&bng[f0 + 4];
    const float4 b0_ = *(const float4*)&bnb[f0],  b1_ = *(const float4*)&bnb[f0 + 4];
    const float cb[8] = { cb0.x, cb0.y, cb0.z, cb0.w, cb1.x, cb1.y, cb1.z, cb1.w };
    const float gg[8] = { g0.x, g0.y, g0.z, g0.w, g1.x, g1.y, g1.z, g1.w };
    const float bb[8] = { b0_.x, b0_.y, b0_.z, b0_.w, b1_.x, b1_.y, b1_.z, b1_.w };
    float v[8];
    #pragma unroll
    for (int j = 0; j < 8; ++j)
        v[j] = fmaxf(((float)acch[j] * dv + cb[j]) * (gg[j] * bnscale) + bb[j], 0.0f);

    if constexpr (!HEAD) {
        size_t o = ((size_t)n << 6) + f0;
        float4 w0 = make_float4(v[0], v[1], v[2], v[3]);
        float4 w1 = make_float4(v[4], v[5], v[6], v[7]);
        if constexpr (RES) {
            float4 o0 = *(const float4*)&hA[o], o1 = *(const float4*)&hA[o + 4];
            w0.x += o0.x; w0.y += o0.y; w0.z += o0.z; w0.w += o0.w;
            w1.x += o1.x; w1.y += o1.y; w1.z += o1.z; w1.w += o1.w;
        }
        *(float4*)&hA[o]     = w0;
        *(float4*)&hA[o + 4] = w1;
    } else {
        float p[3];
        #pragma unroll
        for (int o = 0; o < 3; ++o) {
            float t = 0.f;
            #pragma unroll
            for (int j = 0; j < 8; ++j) t += v[j] * HWs[o * 67 + f0 + j];
            p[o] = t;
        }
        // reduce across the 8 octets of this node (lanes differ in bits 0..2)
        #pragma unroll
        for (int mask = 1; mask < 8; mask <<= 1) {
            #pragma unroll
            for (int o = 0; o < 3; ++o) p[o] += __shfl_xor(p[o], mask, 64);
        }
        if (oct == 0) {
            float by0 = byp[n * 3], by1 = byp[n * 3 + 1], by2 = byp[n * 3 + 2];
            #pragma unroll
            for (int o = 0; o < 3; ++o)
                p[o] += by0 * HWs[o * 67 + 64] + by1 * HWs[o * 67 + 65] + by2 * HWs[o * 67 + 66]
                      + HWs[201 + o];
            float kappa = fminf(fmaxf(p[0] * 5.0f + 2.5f, 0.2f), 10.0f);
            float tau   = fminf(fmaxf(p[2] + 0.5f, 0.05f), 2.0f);
            out[(size_t)n * 3]     = kappa;
            out[(size_t)n * 3 + 1] = p[1];
            out[(size_t)n * 3 + 2] = tau;
        }
    }
}

extern "C" void kernel_launch(void* const* d_in, const int* in_sizes, int n_in,
                              void* d_out, int out_size, void* d_ws, size_t ws_size,
                              hipStream_t stream) {
    const float* x     = (const float*)d_in[0];
    const int*   ei    = (const int*)d_in[1];
    const int*   row   = ei;
    const int*   col   = ei + NE;
    const float* projW = (const float*)d_in[2];
    const float* projb = (const float*)d_in[3];
    const float* convW[3] = { (const float*)d_in[4], (const float*)d_in[8],  (const float*)d_in[12] };
    const float* convb[3] = { (const float*)d_in[5], (const float*)d_in[9],  (const float*)d_in[13] };
    const float* bng[3]   = { (const float*)d_in[6], (const float*)d_in[10], (const float*)d_in[14] };
    const float* bnb[3]   = { (const float*)d_in[7], (const float*)d_in[11], (const float*)d_in[15] };
    const float* bypW  = (const float*)d_in[16];
    const float* bypb  = (const float*)d_in[17];
    const float* headW = (const float*)d_in[18];
    const float* headb = (const float*)d_in[19];
    float* out = (float*)d_out;

    float*    ws   = (float*)d_ws;
    float*    dinv = ws;                                  // 102400 floats
    float*    hA   = ws + 102400;                         // NN*64 fp32
    _Float16* hBh  = (_Float16*)(hA + (size_t)NN * 64);   // NN*64 fp16
    float*    byp  = (float*)(hBh + (size_t)NN * 64);     // NN*3 (+pad)
    int*      off     = (int*)(byp + 300032);             // NN+1 (pad 100096)
    int*      csr_row = off + 100096;                     // NE
    int*      bcnt    = csr_row + NE;                     // NBUK+1 (pad 784)
    int*      bcur    = bcnt + 784;                       // NBUK
    unsigned* tmp     = (unsigned*)hA;                    // aliases hA (consumed before proj)

    // bucketed CSR build (+dinv +off)
    k_zerob<<<1, 1024, 0, stream>>>(bcnt);
    k_bhist<<<256, 256, 0, stream>>>(col, bcnt);
    k_bscan<<<1, 1024, 0, stream>>>(bcnt, bcur);
    k_bucket<<<NCHUNK, 256, 0, stream>>>(row, col, bcur, tmp);
    k_build<<<NBUK, 256, 0, stream>>>(tmp, bcnt, off, dinv, csr_row);

    // proj: hA = x @ projW.T + projb  (fp32 out) + byp = x @ bypW.T + bypb
    k_gemm<128, false, true><<<(NN + 63) / 64, 256, 0, stream>>>(
        x, projW, projb, nullptr, hA, nullptr, bypW, bypb, byp, NN);

    for (int l = 0; l < 3; l++) {
        // hBh = (hA @ convW.T) * dinv   (fp16 out, bias deferred)
        k_gemm<64, true, false><<<(NN + 63) / 64, 256, 0, stream>>>(
            hA, convW[l], nullptr, dinv, nullptr, hBh, nullptr, nullptr, nullptr, NN);
        if (l < 2)
            k_gather<true, false><<<NN / 32, 256, 0, stream>>>(
                hBh, dinv, off, csr_row, convb[l], bng[l], bnb[l], hA,
                nullptr, nullptr, nullptr, nullptr);
        else
            k_gather<false, true><<<NN / 32, 256, 0, stream>>>(
                hBh, dinv, off, csr_row, convb[l], bng[l], bnb[l], nullptr,
                byp, headW, headb, out);
    }
}